// Round 2
// baseline (139.251 us; speedup 1.0000x reference)
//
#include <hip/hip_runtime.h>

#define DIM 256
#define EMB 128
#define HID 128
#define BB  4
#define NB  512
#define NU  512

// ---------------------------------------------------------------------------
// Branch-free exact GELU: x * 0.5 * (1 + erf(x/sqrt(2)))
// erf via Abramowitz-Stegun 7.1.26 (max abs err 1.5e-7), no divergence.
// ~13 VALU + 2 trans (rcp, exp2) per call.
// ---------------------------------------------------------------------------
__device__ __forceinline__ float gelu_exact(float x) {
    float z  = x * 0.70710678118654752f;      // x / sqrt(2)
    float az = __builtin_fabsf(z);
    float t  = __builtin_amdgcn_rcpf(__builtin_fmaf(0.3275911f, az, 1.0f));
    float p  = __builtin_fmaf(1.061405429f, t, -1.453152027f);
    p = __builtin_fmaf(p, t, 1.421413741f);
    p = __builtin_fmaf(p, t, -0.284496736f);
    p = __builtin_fmaf(p, t, 0.254829592f);
    p = p * t;
    float ea = az * -1.4426950408889634f;     // -log2(e) * az
    float e  = __builtin_amdgcn_exp2f(ea * az);   // exp(-az^2)
    float erf_abs = __builtin_fmaf(-p, e, 1.0f);
    float erf = __builtin_copysignf(erf_abs, x);  // sign(z) == sign(x)
    float hx = 0.5f * x;
    return __builtin_fmaf(hx, erf, hx);
}

// ---------------------------------------------------------------------------
// Kernel 1: projections (≈1% of total FLOPs).
//   blocks [0, 512):   bp[b,n,h] = sum_d bin[b,n,d]*W1[d,h] + b1[h]   (4 rows/blk)
//   blocks [512,1024): up[b,u,h] = sum_e unit[b,u,e]*W1[256+e,h]      (4 rows/blk)
// A-rows staged in LDS (broadcast reads); W1 columns coalesced per wave.
// ---------------------------------------------------------------------------
__global__ __launch_bounds__(256) void proj_kernel(
    const float* __restrict__ bin, const float* __restrict__ unit,
    const float* __restrict__ W1,  const float* __restrict__ b1,
    float* __restrict__ bp, float* __restrict__ up)
{
    __shared__ float As[4 * DIM];               // 4 KB max (4 rows x 256)
    const int blk   = blockIdx.x;
    const bool isBin = (blk < (BB * NB / 4));
    const int inD   = isBin ? DIM : EMB;
    const float* src = isBin ? bin : unit;
    const int rowBase = (isBin ? blk : blk - (BB * NB / 4)) * 4;
    const float* wBase = W1 + (isBin ? 0 : DIM * HID);
    float* dst = isBin ? bp : up;

    const int t = threadIdx.x;

    // stage 4 input rows (contiguous in global) into LDS
    const float4* g4 = (const float4*)(src + (size_t)rowBase * inD);
    float4* s4 = (float4*)As;
    const int nf4 = inD;                        // 4*inD/4 float4s
    for (int i = t; i < nf4; i += 256) s4[i] = g4[i];
    __syncthreads();

    const int h  = t & 127;
    const int rg = t >> 7;                      // 0/1 -> rows rg*2 + {0,1}
    float acc0 = 0.f, acc1 = 0.f;
    const float* a0base = &As[(rg * 2 + 0) * inD];
    const float* a1base = &As[(rg * 2 + 1) * inD];

    for (int d = 0; d < inD; d += 4) {
        float w0 = wBase[(d + 0) * HID + h];    // coalesced per wave
        float w1 = wBase[(d + 1) * HID + h];
        float w2 = wBase[(d + 2) * HID + h];
        float w3 = wBase[(d + 3) * HID + h];
        float4 a0 = *(const float4*)&a0base[d]; // wave-uniform -> broadcast
        float4 a1 = *(const float4*)&a1base[d];
        acc0 = __builtin_fmaf(a0.x, w0, acc0);
        acc0 = __builtin_fmaf(a0.y, w1, acc0);
        acc0 = __builtin_fmaf(a0.z, w2, acc0);
        acc0 = __builtin_fmaf(a0.w, w3, acc0);
        acc1 = __builtin_fmaf(a1.x, w0, acc1);
        acc1 = __builtin_fmaf(a1.y, w1, acc1);
        acc1 = __builtin_fmaf(a1.z, w2, acc1);
        acc1 = __builtin_fmaf(a1.w, w3, acc1);
    }
    const float bias = isBin ? b1[h] : 0.f;
    dst[(size_t)(rowBase + rg * 2 + 0) * HID + h] = acc0 + bias;
    dst[(size_t)(rowBase + rg * 2 + 1) * HID + h] = acc1 + bias;
}

// ---------------------------------------------------------------------------
// Kernel 2: out[b,n,u] = b2 + sum_h W2[h] * gelu(bp[b,n,h] + up[b,u,h])
// Tile: TN=16 (y), TU=64 (x). 256 threads, 4 outputs/thread.
// LDS: sBp[16][128] natural (wave-uniform broadcast reads),
//      sUp transposed [h][u] with XOR swizzle (u ^ (h&28)):
//        reads 2-way (free), transpose-scatter writes 4-way,
//      sW2[128] (uniform broadcast reads, no global loads in hot loop).
// LDS total = 8192 + 32768 + 512 = 41472 B -> 3 blocks/CU (LDS-capped),
//   12 waves/CU, enough TLP for a VALU-bound loop.
// ---------------------------------------------------------------------------
__global__ __launch_bounds__(256) void head_kernel(
    const float* __restrict__ bp, const float* __restrict__ up,
    const float* __restrict__ W2, const float* __restrict__ b2p,
    float* __restrict__ out)
{
    __shared__ float sBp[16 * HID];             // 8 KB
    __shared__ float sUp[HID * 64];             // 32 KB, [h][u ^ (h&28)]
    __shared__ float sW2[HID];                  // 512 B

    const int b  = blockIdx.z;
    const int n0 = blockIdx.y * 16;
    const int u0 = blockIdx.x * 64;
    const int t  = threadIdx.x;

    // ---- stage W2 (128 floats) and bp tile (2048 contiguous floats)
    if (t < 32) ((float4*)sW2)[t] = ((const float4*)W2)[t];
    {
        const float4* g = (const float4*)(bp + ((size_t)b * NB + n0) * HID);
        float4* s = (float4*)sBp;
        s[t]       = g[t];
        s[t + 256] = g[t + 256];
    }

    // ---- stage up tile transposed+swizzled: 8192 floats
    {
        const float4* g = (const float4*)(up + ((size_t)b * NU + u0) * HID);
#pragma unroll
        for (int i = 0; i < 8; ++i) {
            int f   = i * 256 + t;              // float4 index in tile
            float4 v = g[f];
            int row = f >> 5;                   // u within tile (128 fl = 32 f4/row)
            int hb  = (f & 31) * 4;             // h base
            int rs  = row ^ (hb & 28);          // (hb+j)&28 == hb&28 for j<4
            sUp[(hb + 0) * 64 + rs] = v.x;
            sUp[(hb + 1) * 64 + rs] = v.y;
            sUp[(hb + 2) * 64 + rs] = v.z;
            sUp[(hb + 3) * 64 + rs] = v.w;
        }
    }
    __syncthreads();

    const int u  = t & 63;
    const int ng = t >> 6;                      // n rows: ng + {0,4,8,12}
    float acc0 = 0.f, acc1 = 0.f, acc2 = 0.f, acc3 = 0.f;
    const float* bpRow = sBp + ng * HID;

    for (int c = 0; c < 32; ++c) {
        const int h  = c * 4;
        const int us = u ^ (h & 28);
        float uv0 = sUp[(h + 0) * 64 + us];     // lane-consecutive, 2-way = free
        float uv1 = sUp[(h + 1) * 64 + us];
        float uv2 = sUp[(h + 2) * 64 + us];
        float uv3 = sUp[(h + 3) * 64 + us];
        float4 w  = *(const float4*)(sW2 + h);  // uniform broadcast
        float4 p0 = *(const float4*)&bpRow[0 * HID + h];   // uniform broadcast
        float4 p1 = *(const float4*)&bpRow[4 * HID + h];
        float4 p2 = *(const float4*)&bpRow[8 * HID + h];
        float4 p3 = *(const float4*)&bpRow[12 * HID + h];

        acc0 = __builtin_fmaf(w.x, gelu_exact(p0.x + uv0), acc0);
        acc0 = __builtin_fmaf(w.y, gelu_exact(p0.y + uv1), acc0);
        acc0 = __builtin_fmaf(w.z, gelu_exact(p0.z + uv2), acc0);
        acc0 = __builtin_fmaf(w.w, gelu_exact(p0.w + uv3), acc0);

        acc1 = __builtin_fmaf(w.x, gelu_exact(p1.x + uv0), acc1);
        acc1 = __builtin_fmaf(w.y, gelu_exact(p1.y + uv1), acc1);
        acc1 = __builtin_fmaf(w.z, gelu_exact(p1.z + uv2), acc1);
        acc1 = __builtin_fmaf(w.w, gelu_exact(p1.w + uv3), acc1);

        acc2 = __builtin_fmaf(w.x, gelu_exact(p2.x + uv0), acc2);
        acc2 = __builtin_fmaf(w.y, gelu_exact(p2.y + uv1), acc2);
        acc2 = __builtin_fmaf(w.z, gelu_exact(p2.z + uv2), acc2);
        acc2 = __builtin_fmaf(w.w, gelu_exact(p2.w + uv3), acc2);

        acc3 = __builtin_fmaf(w.x, gelu_exact(p3.x + uv0), acc3);
        acc3 = __builtin_fmaf(w.y, gelu_exact(p3.y + uv1), acc3);
        acc3 = __builtin_fmaf(w.z, gelu_exact(p3.z + uv2), acc3);
        acc3 = __builtin_fmaf(w.w, gelu_exact(p3.w + uv3), acc3);
    }

    const float b2 = *b2p;
    float* o = out + ((size_t)b * NB + n0 + ng) * NU + u0 + u;
    o[0]          = acc0 + b2;                  // row ng
    o[4 * NU]     = acc1 + b2;                  // row ng+4
    o[8 * NU]     = acc2 + b2;                  // row ng+8
    o[12 * NU]    = acc3 + b2;                  // row ng+12
}

// ---------------------------------------------------------------------------
extern "C" void kernel_launch(void* const* d_in, const int* in_sizes, int n_in,
                              void* d_out, int out_size, void* d_ws, size_t ws_size,
                              hipStream_t stream)
{
    const float* bin  = (const float*)d_in[0];
    const float* unit = (const float*)d_in[1];
    const float* W1   = (const float*)d_in[2];
    const float* b1   = (const float*)d_in[3];
    const float* W2   = (const float*)d_in[4];
    const float* b2   = (const float*)d_in[5];
    float* out = (float*)d_out;

    float* bp = (float*)d_ws;                   // [B*NB, HID] = 1 MB
    float* up = bp + (size_t)BB * NB * HID;     // [B*NU, HID] = 1 MB

    proj_kernel<<<dim3(BB * NB / 4 + BB * NU / 4), 256, 0, stream>>>(
        bin, unit, W1, b1, bp, up);
    head_kernel<<<dim3(NU / 64, NB / 16, BB), 256, 0, stream>>>(
        bp, up, W2, b2, out);
}

// Round 3
// 132.362 us; speedup vs baseline: 1.0520x; 1.0520x over previous
//
#include <hip/hip_runtime.h>

#define DIM 256
#define EMB 128
#define HID 128
#define BB  4
#define NB  512
#define NU  512
#define PR  8      // proj: rows per block
#define DC  64     // proj: W1 d-chunk staged in LDS

// ---------------------------------------------------------------------------
// Branch-free exact GELU: x * 0.5 * (1 + erf(x/sqrt(2)))
// erf via Abramowitz-Stegun 7.1.26 (max abs err 1.5e-7), no divergence.
// ---------------------------------------------------------------------------
__device__ __forceinline__ float gelu_exact(float x) {
    float z  = x * 0.70710678118654752f;      // x / sqrt(2)
    float az = __builtin_fabsf(z);
    float t  = __builtin_amdgcn_rcpf(__builtin_fmaf(0.3275911f, az, 1.0f));
    float p  = __builtin_fmaf(1.061405429f, t, -1.453152027f);
    p = __builtin_fmaf(p, t, 1.421413741f);
    p = __builtin_fmaf(p, t, -0.284496736f);
    p = __builtin_fmaf(p, t, 0.254829592f);
    p = p * t;
    float ea = az * -1.4426950408889634f;     // -log2(e) * az
    float e  = __builtin_amdgcn_exp2f(ea * az);   // exp(-az^2)
    float erf_abs = __builtin_fmaf(-p, e, 1.0f);
    float erf = __builtin_copysignf(erf_abs, x);
    float hx = 0.5f * x;
    return __builtin_fmaf(hx, erf, hx);
}

// ---------------------------------------------------------------------------
// Kernel 1: projections. PR=8 rows/block.
//   blocks [0,256):   bp[b,n,h] = sum_d bin[..]*W1[d,h] + b1[h]
//   blocks [256,512): up[b,u,h] = sum_e unit[..]*W1[256+e,h]
// W1 staged through LDS in DC=64-row chunks (coalesced float4 global reads);
// column reads then hit LDS (lanes h-consecutive -> 2-way = free), replacing
// the round-2 version's 256 scalar L2-latency-bound global loads per thread.
// LDS = 32768 (Ws) + 8192 (As) = 40960 -> 4 blocks/CU.
// ---------------------------------------------------------------------------
__global__ __launch_bounds__(256) void proj_kernel(
    const float* __restrict__ bin, const float* __restrict__ unit,
    const float* __restrict__ W1,  const float* __restrict__ b1,
    float* __restrict__ bp, float* __restrict__ up)
{
    __shared__ float Ws[DC * HID];              // 32 KB
    __shared__ float As[PR * DIM];              // 8 KB (bin); unit uses half

    const int blk    = blockIdx.x;
    const bool isBin = (blk < (BB * NB / PR));
    const int inD    = isBin ? DIM : EMB;
    const float* src = isBin ? bin : unit;
    const int rowBase = (isBin ? blk : blk - (BB * NB / PR)) * PR;
    const float* wBase = W1 + (isBin ? 0 : DIM * HID);
    float* dst = isBin ? bp : up;

    const int t = threadIdx.x;

    // stage PR input rows (contiguous in global) into LDS
    {
        const float4* g4 = (const float4*)(src + (size_t)rowBase * inD);
        float4* s4 = (float4*)As;
        const int nf4 = PR * inD / 4;           // 512 (bin) / 256 (unit)
        for (int i = t; i < nf4; i += 256) s4[i] = g4[i];
    }

    const int h  = t & 127;
    const int rg = t >> 7;                      // rows rg*4 + {0..3}
    float acc0 = 0.f, acc1 = 0.f, acc2 = 0.f, acc3 = 0.f;
    const float* aBase = As + (rg * 4) * inD;

    for (int d0 = 0; d0 < inD; d0 += DC) {
        __syncthreads();                        // Ws free (and As staged on iter 0)
        {   // stage W1[d0..d0+DC) x HID : 2048 float4, 8 per thread, coalesced
            const float4* g4 = (const float4*)(wBase + (size_t)d0 * HID);
            float4* s4 = (float4*)Ws;
#pragma unroll
            for (int i = 0; i < 8; ++i) s4[t + i * 256] = g4[t + i * 256];
        }
        __syncthreads();
#pragma unroll 4
        for (int dd = 0; dd < DC; dd += 4) {
            const int d = d0 + dd;
            float w0 = Ws[(dd + 0) * HID + h];  // lanes h-consecutive: free
            float w1 = Ws[(dd + 1) * HID + h];
            float w2 = Ws[(dd + 2) * HID + h];
            float w3 = Ws[(dd + 3) * HID + h];
            float4 a0 = *(const float4*)&aBase[0 * inD + d];  // uniform bcast
            float4 a1 = *(const float4*)&aBase[1 * inD + d];
            float4 a2 = *(const float4*)&aBase[2 * inD + d];
            float4 a3 = *(const float4*)&aBase[3 * inD + d];
            acc0 = __builtin_fmaf(a0.x, w0, acc0);
            acc0 = __builtin_fmaf(a0.y, w1, acc0);
            acc0 = __builtin_fmaf(a0.z, w2, acc0);
            acc0 = __builtin_fmaf(a0.w, w3, acc0);
            acc1 = __builtin_fmaf(a1.x, w0, acc1);
            acc1 = __builtin_fmaf(a1.y, w1, acc1);
            acc1 = __builtin_fmaf(a1.z, w2, acc1);
            acc1 = __builtin_fmaf(a1.w, w3, acc1);
            acc2 = __builtin_fmaf(a2.x, w0, acc2);
            acc2 = __builtin_fmaf(a2.y, w1, acc2);
            acc2 = __builtin_fmaf(a2.z, w2, acc2);
            acc2 = __builtin_fmaf(a2.w, w3, acc2);
            acc3 = __builtin_fmaf(a3.x, w0, acc3);
            acc3 = __builtin_fmaf(a3.y, w1, acc3);
            acc3 = __builtin_fmaf(a3.z, w2, acc3);
            acc3 = __builtin_fmaf(a3.w, w3, acc3);
        }
    }
    const float bias = isBin ? b1[h] : 0.f;
    float* o = dst + (size_t)(rowBase + rg * 4) * HID + h;
    o[0 * HID] = acc0 + bias;                   // lanes h-consecutive: coalesced
    o[1 * HID] = acc1 + bias;
    o[2 * HID] = acc2 + bias;
    o[3 * HID] = acc3 + bias;
}

// ---------------------------------------------------------------------------
// Kernel 2: out[b,n,u] = b2 + sum_h W2[h] * gelu(bp[b,n,h] + up[b,u,h])
// Tile TN=16 x TU=64, 256 threads, 4 outputs/thread.
// sBp[16][128] natural (wave-uniform broadcast reads).
// sUp[u=64][h=128] with 16B XOR swizzle (storage chunk = chunk ^ (u&7)):
//   inner-loop read = ONE ds_read_b128, bank-groups (c^(u&7)) span all 8
//   uniformly -> exact 8-cycle wave64 minimum (conflict-free); same for the
//   staging ds_write_b128.
// W2/b1/b2 reads are loop-uniform -> compiler scalar loads (no LDS needed).
// LDS = 8192 + 32768 = 40960 B -> 4 blocks/CU; grid = 1024 = one full round.
// ---------------------------------------------------------------------------
__global__ __launch_bounds__(256) void head_kernel(
    const float* __restrict__ bp, const float* __restrict__ up,
    const float* __restrict__ W2, const float* __restrict__ b2p,
    float* __restrict__ out)
{
    __shared__ float sBp[16 * HID];             // 8 KB
    __shared__ float sUp[64 * HID];             // 32 KB, [u][chunk^ (u&7)]

    const int b  = blockIdx.z;
    const int n0 = blockIdx.y * 16;
    const int u0 = blockIdx.x * 64;
    const int t  = threadIdx.x;

    // ---- stage bp tile: 2048 contiguous floats
    {
        const float4* g = (const float4*)(bp + ((size_t)b * NB + n0) * HID);
        float4* s = (float4*)sBp;
        s[t]       = g[t];
        s[t + 256] = g[t + 256];
    }

    // ---- stage up tile [64][128], 16B-chunk XOR swizzle: 2048 float4
    {
        const float4* g = (const float4*)(up + ((size_t)b * NU + u0) * HID);
#pragma unroll
        for (int i = 0; i < 8; ++i) {
            int f   = i * 256 + t;              // float4 index in tile
            float4 v = g[f];
            int row = f >> 5;                   // u within tile (32 f4/row)
            int st  = (f & 31) ^ (row & 7);     // swizzled storage chunk
            *(float4*)&sUp[row * HID + st * 4] = v;
        }
    }
    __syncthreads();

    const int u    = t & 63;
    const int ng   = t >> 6;                    // n rows: ng + {0,4,8,12}
    const int sswz = (u & 7) << 2;              // float-offset xor
    float acc0 = 0.f, acc1 = 0.f, acc2 = 0.f, acc3 = 0.f;
    const float* bpRow = sBp + ng * HID;
    const float* upRow = sUp + u * HID;
    const float b2 = *b2p;

    for (int c = 0; c < 32; ++c) {
        const int h = c * 4;
        float4 uv = *(const float4*)&upRow[h ^ sswz];      // 1x b128, conflict-free
        float4 w  = *(const float4*)(W2 + h);              // uniform -> s_load
        float4 p0 = *(const float4*)&bpRow[0 * HID + h];   // uniform bcast
        float4 p1 = *(const float4*)&bpRow[4 * HID + h];
        float4 p2 = *(const float4*)&bpRow[8 * HID + h];
        float4 p3 = *(const float4*)&bpRow[12 * HID + h];

        acc0 = __builtin_fmaf(w.x, gelu_exact(p0.x + uv.x), acc0);
        acc0 = __builtin_fmaf(w.y, gelu_exact(p0.y + uv.y), acc0);
        acc0 = __builtin_fmaf(w.z, gelu_exact(p0.z + uv.z), acc0);
        acc0 = __builtin_fmaf(w.w, gelu_exact(p0.w + uv.w), acc0);

        acc1 = __builtin_fmaf(w.x, gelu_exact(p1.x + uv.x), acc1);
        acc1 = __builtin_fmaf(w.y, gelu_exact(p1.y + uv.y), acc1);
        acc1 = __builtin_fmaf(w.z, gelu_exact(p1.z + uv.z), acc1);
        acc1 = __builtin_fmaf(w.w, gelu_exact(p1.w + uv.w), acc1);

        acc2 = __builtin_fmaf(w.x, gelu_exact(p2.x + uv.x), acc2);
        acc2 = __builtin_fmaf(w.y, gelu_exact(p2.y + uv.y), acc2);
        acc2 = __builtin_fmaf(w.z, gelu_exact(p2.z + uv.z), acc2);
        acc2 = __builtin_fmaf(w.w, gelu_exact(p2.w + uv.w), acc2);

        acc3 = __builtin_fmaf(w.x, gelu_exact(p3.x + uv.x), acc3);
        acc3 = __builtin_fmaf(w.y, gelu_exact(p3.y + uv.y), acc3);
        acc3 = __builtin_fmaf(w.z, gelu_exact(p3.z + uv.z), acc3);
        acc3 = __builtin_fmaf(w.w, gelu_exact(p3.w + uv.w), acc3);
    }

    float* o = out + ((size_t)b * NB + n0 + ng) * NU + u0 + u;
    o[0]       = acc0 + b2;                     // row ng
    o[4 * NU]  = acc1 + b2;                     // row ng+4
    o[8 * NU]  = acc2 + b2;                     // row ng+8
    o[12 * NU] = acc3 + b2;                     // row ng+12
}

// ---------------------------------------------------------------------------
extern "C" void kernel_launch(void* const* d_in, const int* in_sizes, int n_in,
                              void* d_out, int out_size, void* d_ws, size_t ws_size,
                              hipStream_t stream)
{
    const float* bin  = (const float*)d_in[0];
    const float* unit = (const float*)d_in[1];
    const float* W1   = (const float*)d_in[2];
    const float* b1   = (const float*)d_in[3];
    const float* W2   = (const float*)d_in[4];
    const float* b2   = (const float*)d_in[5];
    float* out = (float*)d_out;

    float* bp = (float*)d_ws;                   // [B*NB, HID] = 1 MB
    float* up = bp + (size_t)BB * NB * HID;     // [B*NU, HID] = 1 MB

    proj_kernel<<<dim3(BB * NB / PR + BB * NU / PR), 256, 0, stream>>>(
        bin, unit, W1, b1, bp, up);
    head_kernel<<<dim3(NU / 64, NB / 16, BB), 256, 0, stream>>>(
        bp, up, W2, b2, out);
}

// Round 4
// 121.263 us; speedup vs baseline: 1.1483x; 1.0915x over previous
//
#include <hip/hip_runtime.h>

#define DIM 256
#define EMB 128
#define HID 128
#define BB  4
#define NB  512
#define NU  512
#define PR  8      // proj: rows per block
#define DC  64     // proj: W1 d-chunk staged in LDS

typedef float f2 __attribute__((ext_vector_type(2)));

// ---------------------------------------------------------------------------
// Packed-pair GELU: returns 2*gelu(x) = x + |x| * erf(|x|/sqrt(2))
//   (caller folds the 0.5 into its epilogue).
// erf via Abramowitz-Stegun 7.1.26 (max abs err 1.5e-7).
// All mul/fma are float2 -> v_pk_*_f32 (gfx950 full-rate packed fp32);
// |x| = max(x,-x) (one pk_max, neg is a free modifier); no copysign needed:
//   x<0: x + |x|*erf_abs = x*(1 - erf_abs) = x*(1 + erf(z)).  ✓
// Per PAIR: ~14 pk VALU + 2 rcp + 2 exp2 (vs 30 VALU + 4 trans scalar).
// ---------------------------------------------------------------------------
__device__ __forceinline__ f2 gelu2x(f2 x) {
    f2 ax = __builtin_elementwise_max(x, -x);          // v_pk_max_f32
    f2 az = ax * 0.70710678118654752f;
    f2 d  = __builtin_elementwise_fma(az, (f2)0.3275911f, (f2)1.0f);
    f2 t;
    t.x = __builtin_amdgcn_rcpf(d.x);
    t.y = __builtin_amdgcn_rcpf(d.y);
    f2 p  = __builtin_elementwise_fma(t, (f2)1.061405429f, (f2)-1.453152027f);
    p = __builtin_elementwise_fma(p, t, (f2)1.421413741f);
    p = __builtin_elementwise_fma(p, t, (f2)-0.284496736f);
    p = __builtin_elementwise_fma(p, t, (f2)0.254829592f);
    p = p * t;
    f2 s  = az * az;
    f2 ea = s * -1.4426950408889634f;                  // -log2(e) * az^2
    f2 e;
    e.x = __builtin_amdgcn_exp2f(ea.x);
    e.y = __builtin_amdgcn_exp2f(ea.y);
    f2 erf_abs = __builtin_elementwise_fma(-p, e, (f2)1.0f);
    return __builtin_elementwise_fma(ax, erf_abs, x);  // = 2*gelu(x)
}

// ---------------------------------------------------------------------------
// Kernel 1: projections (unchanged from round 3; ~5% of total).
// ---------------------------------------------------------------------------
__global__ __launch_bounds__(256) void proj_kernel(
    const float* __restrict__ bin, const float* __restrict__ unit,
    const float* __restrict__ W1,  const float* __restrict__ b1,
    float* __restrict__ bp, float* __restrict__ up)
{
    __shared__ float Ws[DC * HID];              // 32 KB
    __shared__ float As[PR * DIM];              // 8 KB (bin); unit uses half

    const int blk    = blockIdx.x;
    const bool isBin = (blk < (BB * NB / PR));
    const int inD    = isBin ? DIM : EMB;
    const float* src = isBin ? bin : unit;
    const int rowBase = (isBin ? blk : blk - (BB * NB / PR)) * PR;
    const float* wBase = W1 + (isBin ? 0 : DIM * HID);
    float* dst = isBin ? bp : up;

    const int t = threadIdx.x;

    {
        const float4* g4 = (const float4*)(src + (size_t)rowBase * inD);
        float4* s4 = (float4*)As;
        const int nf4 = PR * inD / 4;
        for (int i = t; i < nf4; i += 256) s4[i] = g4[i];
    }

    const int h  = t & 127;
    const int rg = t >> 7;
    float acc0 = 0.f, acc1 = 0.f, acc2 = 0.f, acc3 = 0.f;
    const float* aBase = As + (rg * 4) * inD;

    for (int d0 = 0; d0 < inD; d0 += DC) {
        __syncthreads();
        {
            const float4* g4 = (const float4*)(wBase + (size_t)d0 * HID);
            float4* s4 = (float4*)Ws;
#pragma unroll
            for (int i = 0; i < 8; ++i) s4[t + i * 256] = g4[t + i * 256];
        }
        __syncthreads();
#pragma unroll 4
        for (int dd = 0; dd < DC; dd += 4) {
            const int d = d0 + dd;
            float w0 = Ws[(dd + 0) * HID + h];
            float w1 = Ws[(dd + 1) * HID + h];
            float w2 = Ws[(dd + 2) * HID + h];
            float w3 = Ws[(dd + 3) * HID + h];
            float4 a0 = *(const float4*)&aBase[0 * inD + d];
            float4 a1 = *(const float4*)&aBase[1 * inD + d];
            float4 a2 = *(const float4*)&aBase[2 * inD + d];
            float4 a3 = *(const float4*)&aBase[3 * inD + d];
            acc0 = __builtin_fmaf(a0.x, w0, acc0);
            acc0 = __builtin_fmaf(a0.y, w1, acc0);
            acc0 = __builtin_fmaf(a0.z, w2, acc0);
            acc0 = __builtin_fmaf(a0.w, w3, acc0);
            acc1 = __builtin_fmaf(a1.x, w0, acc1);
            acc1 = __builtin_fmaf(a1.y, w1, acc1);
            acc1 = __builtin_fmaf(a1.z, w2, acc1);
            acc1 = __builtin_fmaf(a1.w, w3, acc1);
            acc2 = __builtin_fmaf(a2.x, w0, acc2);
            acc2 = __builtin_fmaf(a2.y, w1, acc2);
            acc2 = __builtin_fmaf(a2.z, w2, acc2);
            acc2 = __builtin_fmaf(a2.w, w3, acc2);
            acc3 = __builtin_fmaf(a3.x, w0, acc3);
            acc3 = __builtin_fmaf(a3.y, w1, acc3);
            acc3 = __builtin_fmaf(a3.z, w2, acc3);
            acc3 = __builtin_fmaf(a3.w, w3, acc3);
        }
    }
    const float bias = isBin ? b1[h] : 0.f;
    float* o = dst + (size_t)(rowBase + rg * 4) * HID + h;
    o[0 * HID] = acc0 + bias;
    o[1 * HID] = acc1 + bias;
    o[2 * HID] = acc2 + bias;
    o[3 * HID] = acc3 + bias;
}

// ---------------------------------------------------------------------------
// Kernel 2: out[b,n,u] = b2 + 0.5 * sum_h W2[h] * gelu2x(bp[b,n,h] + up[b,u,h])
// Tile TN=16 x TU=64, 256 threads, 4 outputs/thread, packed f32 pairs.
// sUp[u][h] with 16B-chunk XOR swizzle (conflict-free b128 reads/writes).
// LDS = 8192 + 32768 = 40960 B -> 4 blocks/CU; grid = 1024 = one full round.
// ---------------------------------------------------------------------------
__global__ __launch_bounds__(256) void head_kernel(
    const float* __restrict__ bp, const float* __restrict__ up,
    const float* __restrict__ W2, const float* __restrict__ b2p,
    float* __restrict__ out)
{
    __shared__ float sBp[16 * HID];             // 8 KB
    __shared__ float sUp[64 * HID];             // 32 KB, [u][chunk ^ (u&7)]

    const int b  = blockIdx.z;
    const int n0 = blockIdx.y * 16;
    const int u0 = blockIdx.x * 64;
    const int t  = threadIdx.x;

    {
        const float4* g = (const float4*)(bp + ((size_t)b * NB + n0) * HID);
        float4* s = (float4*)sBp;
        s[t]       = g[t];
        s[t + 256] = g[t + 256];
    }
    {
        const float4* g = (const float4*)(up + ((size_t)b * NU + u0) * HID);
#pragma unroll
        for (int i = 0; i < 8; ++i) {
            int f   = i * 256 + t;
            float4 v = g[f];
            int row = f >> 5;
            int st  = (f & 31) ^ (row & 7);
            *(float4*)&sUp[row * HID + st * 4] = v;
        }
    }
    __syncthreads();

    const int u    = t & 63;
    const int ng   = t >> 6;                    // n rows: ng + {0,4,8,12}
    const int sswz = (u & 7) << 2;
    f2 acc0 = (f2)0.f, acc1 = (f2)0.f, acc2 = (f2)0.f, acc3 = (f2)0.f;
    const float* bpRow = sBp + ng * HID;
    const float* upRow = sUp + u * HID;
    const float b2 = *b2p;

    for (int c = 0; c < 32; ++c) {
        const int h = c * 4;
        float4 uv4 = *(const float4*)&upRow[h ^ sswz];     // 1x b128, conflict-free
        float4 w4  = *(const float4*)(W2 + h);             // uniform -> s_load
        float4 q0  = *(const float4*)&bpRow[0 * HID + h];  // uniform bcast
        float4 q1  = *(const float4*)&bpRow[4 * HID + h];
        float4 q2  = *(const float4*)&bpRow[8 * HID + h];
        float4 q3  = *(const float4*)&bpRow[12 * HID + h];
        f2 uvA = {uv4.x, uv4.y}, uvB = {uv4.z, uv4.w};
        f2 wA  = {w4.x,  w4.y},  wB  = {w4.z,  w4.w};

        acc0 = __builtin_elementwise_fma(wA, gelu2x((f2){q0.x, q0.y} + uvA), acc0);
        acc0 = __builtin_elementwise_fma(wB, gelu2x((f2){q0.z, q0.w} + uvB), acc0);
        acc1 = __builtin_elementwise_fma(wA, gelu2x((f2){q1.x, q1.y} + uvA), acc1);
        acc1 = __builtin_elementwise_fma(wB, gelu2x((f2){q1.z, q1.w} + uvB), acc1);
        acc2 = __builtin_elementwise_fma(wA, gelu2x((f2){q2.x, q2.y} + uvA), acc2);
        acc2 = __builtin_elementwise_fma(wB, gelu2x((f2){q2.z, q2.w} + uvB), acc2);
        acc3 = __builtin_elementwise_fma(wA, gelu2x((f2){q3.x, q3.y} + uvA), acc3);
        acc3 = __builtin_elementwise_fma(wB, gelu2x((f2){q3.z, q3.w} + uvB), acc3);
    }

    float* o = out + ((size_t)b * NB + n0 + ng) * NU + u0 + u;
    o[0]       = __builtin_fmaf(0.5f, acc0.x + acc0.y, b2);   // row ng
    o[4 * NU]  = __builtin_fmaf(0.5f, acc1.x + acc1.y, b2);   // row ng+4
    o[8 * NU]  = __builtin_fmaf(0.5f, acc2.x + acc2.y, b2);   // row ng+8
    o[12 * NU] = __builtin_fmaf(0.5f, acc3.x + acc3.y, b2);   // row ng+12
}

// ---------------------------------------------------------------------------
extern "C" void kernel_launch(void* const* d_in, const int* in_sizes, int n_in,
                              void* d_out, int out_size, void* d_ws, size_t ws_size,
                              hipStream_t stream)
{
    const float* bin  = (const float*)d_in[0];
    const float* unit = (const float*)d_in[1];
    const float* W1   = (const float*)d_in[2];
    const float* b1   = (const float*)d_in[3];
    const float* W2   = (const float*)d_in[4];
    const float* b2   = (const float*)d_in[5];
    float* out = (float*)d_out;

    float* bp = (float*)d_ws;                   // [B*NB, HID] = 1 MB
    float* up = bp + (size_t)BB * NB * HID;     // [B*NU, HID] = 1 MB

    proj_kernel<<<dim3(BB * NB / PR + BB * NU / PR), 256, 0, stream>>>(
        bin, unit, W1, b1, bp, up);
    head_kernel<<<dim3(NU / 64, NB / 16, BB), 256, 0, stream>>>(
        bp, up, W2, b2, out);
}